// Round 3
// baseline (1346.367 us; speedup 1.0000x reference)
//
#include <hip/hip_runtime.h>
#include <cstddef>

typedef _Float16 f16;
typedef __attribute__((ext_vector_type(8))) _Float16 f16x8;
typedef __attribute__((ext_vector_type(4))) _Float16 f16x4;
typedef __attribute__((ext_vector_type(2))) _Float16 f16x2;
typedef __attribute__((ext_vector_type(4))) float f32x4;
typedef __attribute__((ext_vector_type(16))) float f32x16;
typedef __attribute__((ext_vector_type(4))) unsigned int u32x4;
typedef unsigned int u32;

// ---------------- workspace layout (bytes) ----------------
#define OFF_NORM  0ull                                // 2 floats (sumsq q, sumsq k)
#define OFF_WT    1024ull                             // f16 Wt[384][128]  (qkv_w transposed)
#define OFF_PWT   (OFF_WT + 384ull*128*2)             // f16 PWt[128][128] (proj_w transposed)
#define OFF_BIASH (OFF_PWT + 128ull*128*2)            // f16 bias[4][256][256]
#define OFF_MASKH (OFF_BIASH + 4ull*256*256*2)        // f16 mask[64][256][256]
#define OFF_QKV   (OFF_MASKH + 64ull*256*256*2)       // f16 qkv[3][1024][4][256][32]
// end = OFF_QKV + 201,326,592 = 210,371,584 bytes (~200.6 MiB)

__device__ __forceinline__ u32 pkh(float a, float b) {
  f16x2 t; t[0] = (f16)a; t[1] = (f16)b;
  return __builtin_bit_cast(u32, t);
}

// ---------------- K1: continuous rel-pos bias MLP (writes f16 directly) ----------------
__global__ void k_bias(const float* __restrict__ rel, const float* __restrict__ fc1w,
                       const float* __restrict__ fc1b, const float* __restrict__ fc2w,
                       const float* __restrict__ fc2b, f16* __restrict__ biash) {
  int n = blockIdx.x, m = threadIdx.x;
  float r0 = rel[(n*256 + m)*2 + 0];
  float r1 = rel[(n*256 + m)*2 + 1];
  float a0 = fc2b[0], a1 = fc2b[1], a2 = fc2b[2], a3 = fc2b[3];
  for (int i = 0; i < 128; ++i) {
    float h = fmaf(r0, fc1w[i], fmaf(r1, fc1w[128 + i], fc1b[i]));
    float t = tanhf(0.7978845608028654f * (h + 0.044715f * h * h * h));
    float g = 0.5f * h * (1.0f + t);
    a0 = fmaf(g, fc2w[i*4 + 0], a0);
    a1 = fmaf(g, fc2w[i*4 + 1], a1);
    a2 = fmaf(g, fc2w[i*4 + 2], a2);
    a3 = fmaf(g, fc2w[i*4 + 3], a3);
  }
  int nm = n*256 + m;
  biash[0*65536 + nm] = (f16)a0;
  biash[1*65536 + nm] = (f16)a1;
  biash[2*65536 + nm] = (f16)a2;
  biash[3*65536 + nm] = (f16)a3;
}

// ---------------- K2: weight transposes (fp32 -> fp16) ----------------
__global__ void k_transpose(const float* __restrict__ qkvw, const float* __restrict__ projw,
                            f16* __restrict__ wt, f16* __restrict__ pwt) {
  int idx = blockIdx.x*256 + threadIdx.x;        // 0..65535
  if (idx < 49152) {                             // Wt[col][k] = qkv_w[k][col]
    int col = idx >> 7, k = idx & 127;
    wt[idx] = (f16)qkvw[k*384 + col];
  } else {
    int p = idx - 49152;                         // PWt[col][k] = proj_w[k][col]
    int col = p >> 7, k = p & 127;
    pwt[p] = (f16)projw[k*128 + col];
  }
}

// ---------------- K3: mask fp32 -> fp16 (4,194,304 elements, 4/thread) ----------------
__global__ void k_cvt(const float* __restrict__ mask, f16* __restrict__ maskh) {
  size_t i = ((size_t)blockIdx.x*256 + threadIdx.x) * 4;
  if (i + 3 < 4194304ull) {
    #pragma unroll
    for (int j = 0; j < 4; ++j) maskh[i + j] = (f16)mask[i + j];
  }
}

// ---------------- K4: QKV GEMM + global sumsq(q),sumsq(k) ----------------
// M=262144 (b,n), K=128, N=384. 16x16x32 f16 MFMA.
// A row = lane&15, k=(lane>>4)*8+j (from global x). B col = lane&15 (from Wt).
// C: col=lane&15, row=(lane>>4)*4+r.
__global__ __launch_bounds__(512, 2)
void k_qkv(const float* __restrict__ x, const f16* __restrict__ wt,
           const float* __restrict__ qkvb, f16* __restrict__ qkv,
           float* __restrict__ norms) {
  int tid = threadIdx.x;
  int wv = tid >> 6, lane = tid & 63;
  int cl = lane & 15, g = lane >> 4;
  int m0 = blockIdx.x*128 + wv*16;

  f16x8 afr[4];
  const float* xrow = x + (size_t)(m0 + cl)*128 + g*8;
  #pragma unroll
  for (int ks = 0; ks < 4; ++ks) {
    f32x4 x0 = *(const f32x4*)(xrow + ks*32);
    f32x4 x1 = *(const f32x4*)(xrow + ks*32 + 4);
    f16x8 a;
    #pragma unroll
    for (int j = 0; j < 4; ++j) { a[j] = (f16)x0[j]; a[j+4] = (f16)x1[j]; }
    afr[ks] = a;
  }

  float sq = 0.f, sk = 0.f;
  #pragma unroll
  for (int nt = 0; nt < 24; ++nt) {
    int col = nt*16 + cl;
    float bcol = qkvb[col];
    f32x4 acc = {bcol, bcol, bcol, bcol};
    const f16* wcol = wt + (size_t)col*128 + g*8;
    #pragma unroll
    for (int ks = 0; ks < 4; ++ks) {
      f16x8 b = *(const f16x8*)(wcol + ks*32);
      acc = __builtin_amdgcn_mfma_f32_16x16x32_f16(afr[ks], b, acc, 0, 0, 0);
    }
    int which = col >> 7, rem = col & 127;
    int hh = rem >> 5, dd = rem & 31;
    #pragma unroll
    for (int r = 0; r < 4; ++r) {
      int row = m0 + g*4 + r;
      int b_ = row >> 8, n = row & 255;
      float v = acc[r];
      if (which == 0) sq += v*v;
      else if (which == 1) sk += v*v;
      qkv[(size_t)which*33554432ull + (size_t)(b_*4 + hh)*8192 + n*32 + dd] = (f16)v;
    }
  }
  #pragma unroll
  for (int o = 32; o > 0; o >>= 1) { sq += __shfl_xor(sq, o); sk += __shfl_xor(sk, o); }
  if (lane == 0) { atomicAdd(norms + 0, sq); atomicAdd(norms + 1, sk); }
}

// ---------------- K5: fused window attention + proj ----------------
// 1 block / window. 8 waves x 32 q-rows. Swapped QK^T (mfma(K,Q)) with 32x32x16:
// C col=lane&31 = q-row n; row = (r&3)+8*(r>>2)+4*hi = kv index m (per 32-tile).
__global__ __launch_bounds__(512, 2)
void k_attn(const f16* __restrict__ qkv, const f16* __restrict__ biash,
            const f16* __restrict__ maskh, const f16* __restrict__ pwt,
            const float* __restrict__ projb, const float* __restrict__ norms,
            const float* __restrict__ taup, float* __restrict__ out) {
  __shared__ f16 vt[8192];     // swizzled V^T: elem(dd,m) at dd*256 + ((m>>3)^(dd&7))*8 + (m&7)
  __shared__ f16 outs[32768];  // swizzled attn-out: elem(n,c) at n*128 + ((c>>3)^(n&7))*8 + (c&7)

  int b = blockIdx.x, w = b & 63;
  int tid = threadIdx.x;
  int wv = tid >> 6, lane = tid & 63;
  int ln = lane & 31, hi = lane >> 5;
  int n0 = wv * 32;

  float tau = fmaxf(taup[0], 0.01f);
  float scale = 1.0f / (sqrtf(norms[0]) * sqrtf(norms[1]) * tau);

  #pragma unroll 1
  for (int h = 0; h < 4; ++h) {
    __syncthreads();
    { // stage V^T (swizzled)
      const f16* vsrc = qkv + 2ull*33554432ull + (size_t)(b*4 + h)*8192;
      #pragma unroll
      for (int it = 0; it < 2; ++it) {
        int idx = tid + it*512;               // f16x8 units, 1024 total
        int m = idx >> 2, dd0 = (idx & 3) * 8;
        f16x8 vv = *(const f16x8*)(vsrc + m*32 + dd0);
        #pragma unroll
        for (int j = 0; j < 8; ++j) {
          int dd = dd0 + j;
          vt[dd*256 + (((m >> 3) ^ (dd & 7)) << 3) + (m & 7)] = vv[j];
        }
      }
    }
    __syncthreads();

    // Q B-frags: col=lane&31 = n, k = dd = 16*ks + hi*8 + j
    const f16* qrow = qkv + (size_t)(b*4 + h)*8192 + (size_t)(n0 + ln)*32 + hi*8;
    f16x8 qf0 = *(const f16x8*)(qrow);
    f16x8 qf1 = *(const f16x8*)(qrow + 16);

    // S^T = K Q^T
    f32x16 sacc[8];
    const f16* kbase = qkv + 33554432ull + (size_t)(b*4 + h)*8192;
    #pragma unroll
    for (int mt = 0; mt < 8; ++mt) {
      f32x16 c;
      #pragma unroll
      for (int r = 0; r < 16; ++r) c[r] = 0.f;
      const f16* krow = kbase + (size_t)(mt*32 + ln)*32 + hi*8;
      f16x8 ka0 = *(const f16x8*)(krow);
      f16x8 ka1 = *(const f16x8*)(krow + 16);
      c = __builtin_amdgcn_mfma_f32_32x32x16_f16(ka0, qf0, c, 0, 0, 0);
      c = __builtin_amdgcn_mfma_f32_32x32x16_f16(ka1, qf1, c, 0, 0, 0);
      sacc[mt] = c;
    }

    // scale + bias + mask, then in-register softmax (row n = n0+ln; partner lane^32)
    const f16* biasrow = biash + (((size_t)(h*256 + n0 + ln)) << 8);
    const f16* maskrow = maskh + (((size_t)(w*256 + n0 + ln)) << 8);
    float mx = -3e38f;
    #pragma unroll
    for (int mt = 0; mt < 8; ++mt) {
      #pragma unroll
      for (int rq = 0; rq < 4; ++rq) {
        int mb = mt*32 + rq*8 + hi*4;          // reg r=rq*4+i <-> m = mt*32 + 8*rq + 4*hi + i
        f16x4 bb = *(const f16x4*)(biasrow + mb);
        f16x4 mm = *(const f16x4*)(maskrow + mb);
        #pragma unroll
        for (int i = 0; i < 4; ++i) {
          float s = fmaf(sacc[mt][rq*4 + i], scale, (float)bb[i] + (float)mm[i]);
          sacc[mt][rq*4 + i] = s;
          mx = fmaxf(mx, s);
        }
      }
    }
    mx = fmaxf(mx, __shfl_xor(mx, 32));
    float sum = 0.f;
    #pragma unroll
    for (int mt = 0; mt < 8; ++mt) {
      #pragma unroll
      for (int r = 0; r < 16; ++r) {
        float p = __expf(sacc[mt][r] - mx);
        sacc[mt][r] = p;
        sum += p;
      }
    }
    sum += __shfl_xor(sum, 32);
    float rs = 1.0f / sum;
    #pragma unroll
    for (int mt = 0; mt < 8; ++mt) {
      #pragma unroll
      for (int r = 0; r < 16; ++r) sacc[mt][r] *= rs;
    }

    // PV: out[n][dd] += P[n][m] V[m][dd], 16 k-steps of 16
    f32x16 oacc;
    #pragma unroll
    for (int r = 0; r < 16; ++r) oacc[r] = 0.f;
    #pragma unroll
    for (int ks = 0; ks < 16; ++ks) {
      int mt = ks >> 1, base = (ks & 1) * 8;
      u32 w0 = pkh(sacc[mt][base+0], sacc[mt][base+1]);   // own mrel (4hi+0, 4hi+1)
      u32 w1 = pkh(sacc[mt][base+4], sacc[mt][base+5]);   // own mrel (8+4hi, 9+4hi)
      u32 w2 = pkh(sacc[mt][base+2], sacc[mt][base+3]);
      u32 w3 = pkh(sacc[mt][base+6], sacc[mt][base+7]);
      asm volatile("v_permlane32_swap_b32 %0, %1" : "+v"(w0), "+v"(w1));
      asm volatile("v_permlane32_swap_b32 %0, %1" : "+v"(w2), "+v"(w3));
      u32x4 av; av[0] = w0; av[1] = w2; av[2] = w1; av[3] = w3;   // k-pairs (0,1)(2,3)(4,5)(6,7)
      f16x8 afrag = __builtin_bit_cast(f16x8, av);
      f16x8 bfrag = *(const f16x8*)&vt[ln*256 + ((((2*ks + hi)) ^ (ln & 7)) << 3)];
      oacc = __builtin_amdgcn_mfma_f32_32x32x16_f16(afrag, bfrag, oacc, 0, 0, 0);
    }

    // write attn-out tile to swizzled LDS (c = h*32 + ln)
    #pragma unroll
    for (int r = 0; r < 16; ++r) {
      int n = n0 + (r & 3) + 8*(r >> 2) + 4*hi;
      int c = h*32 + ln;
      outs[n*128 + ((((c >> 3) ^ (n & 7))) << 3) + (c & 7)] = (f16)oacc[r];
    }
  }
  __syncthreads();

  // fused proj: (256x128) @ (128x128) + b, per wave: rows n0..n0+31
  {
    f16x8 afr[8];
    int n = n0 + ln;
    #pragma unroll
    for (int ks = 0; ks < 8; ++ks)
      afr[ks] = *(const f16x8*)&outs[n*128 + (((2*ks + hi) ^ (n & 7)) << 3)];
    #pragma unroll
    for (int ct = 0; ct < 4; ++ct) {
      int cout = ct*32 + ln;
      float pb = projb[cout];
      f32x16 pacc;
      #pragma unroll
      for (int r = 0; r < 16; ++r) pacc[r] = pb;
      const f16* prow = pwt + (size_t)cout*128 + hi*8;
      #pragma unroll
      for (int ks = 0; ks < 8; ++ks) {
        f16x8 bfr = *(const f16x8*)(prow + ks*16);
        pacc = __builtin_amdgcn_mfma_f32_32x32x16_f16(afr[ks], bfr, pacc, 0, 0, 0);
      }
      #pragma unroll
      for (int r = 0; r < 16; ++r) {
        int nn = n0 + (r & 3) + 8*(r >> 2) + 4*hi;
        out[((size_t)b*256 + nn)*128 + cout] = pacc[r];
      }
    }
  }
}

// ---------------- launch ----------------
extern "C" void kernel_launch(void* const* d_in, const int* in_sizes, int n_in,
                              void* d_out, int out_size, void* d_ws, size_t ws_size,
                              hipStream_t stream) {
  const float* x     = (const float*)d_in[0];
  const float* mask  = (const float*)d_in[1];
  const float* rel   = (const float*)d_in[2];
  const float* qkvw  = (const float*)d_in[3];
  const float* qkvb  = (const float*)d_in[4];
  const float* projw = (const float*)d_in[5];
  const float* projb = (const float*)d_in[6];
  const float* fc1w  = (const float*)d_in[7];
  const float* fc1b  = (const float*)d_in[8];
  const float* fc2w  = (const float*)d_in[9];
  const float* fc2b  = (const float*)d_in[10];
  const float* tau   = (const float*)d_in[11];
  float* outp = (float*)d_out;
  char* ws = (char*)d_ws;

  float* norms  = (float*)(ws + OFF_NORM);
  f16*   wt     = (f16*)(ws + OFF_WT);
  f16*   pwt    = (f16*)(ws + OFF_PWT);
  f16*   biash  = (f16*)(ws + OFF_BIASH);
  f16*   maskh  = (f16*)(ws + OFF_MASKH);
  f16*   qkv    = (f16*)(ws + OFF_QKV);

  hipMemsetAsync(norms, 0, 8, stream);
  k_bias<<<256, 256, 0, stream>>>(rel, fc1w, fc1b, fc2w, fc2b, biash);
  k_transpose<<<256, 256, 0, stream>>>(qkvw, projw, wt, pwt);
  k_cvt<<<4096, 256, 0, stream>>>(mask, maskh);
  k_qkv<<<2048, 512, 0, stream>>>(x, wt, qkvb, qkv, norms);
  k_attn<<<1024, 512, 0, stream>>>(qkv, biash, maskh, pwt, projb, norms, tau, outp);
}

// Round 4
// 661.733 us; speedup vs baseline: 2.0346x; 2.0346x over previous
//
#include <hip/hip_runtime.h>
#include <cstddef>

typedef _Float16 f16;
typedef __attribute__((ext_vector_type(8))) _Float16 f16x8;
typedef __attribute__((ext_vector_type(4))) _Float16 f16x4;
typedef __attribute__((ext_vector_type(2))) _Float16 f16x2;
typedef __attribute__((ext_vector_type(4))) float f32x4;
typedef __attribute__((ext_vector_type(16))) float f32x16;
typedef __attribute__((ext_vector_type(4))) unsigned int u32x4;
typedef unsigned int u32;

// ---------------- workspace layout (bytes) ----------------
#define OFF_NORM  0ull                                // 2 floats (sumsq q, sumsq k)
#define OFF_WT    1024ull                             // f16 Wt[384][128]  (qkv_w transposed)
#define OFF_PWT   (OFF_WT + 384ull*128*2)             // f16 PWt[128][128] (proj_w transposed)
#define OFF_BIASP (OFF_PWT + 128ull*128*2)            // f16 bias_p[4][256][2][128] (permuted)
#define OFF_MASKP (OFF_BIASP + 4ull*256*256*2)        // f16 mask_p[64][256][2][128] (permuted)
#define OFF_QKV   (OFF_MASKP + 64ull*256*256*2)       // f16 q[1024][4][256][32], k same, vT[1024][4][32][256]
// end = OFF_QKV + 201,326,592 = 210,371,584 bytes (== round-3 proven size)

#define QSZ 33554432ull   // elements per q/k/v section

__device__ __forceinline__ u32 pkh(float a, float b) {
  f16x2 t; t[0] = (f16)a; t[1] = (f16)b;
  return __builtin_bit_cast(u32, t);
}

// permuted index for (n-row-local table): [(row)*2 + hi]*128 + mt*16 + rq*4 + i
// where m = mt*32 + rq*8 + hi*4 + i
__device__ __forceinline__ int permidx(int m) {
  int mt = m >> 5, rq = (m >> 3) & 3, hi = (m >> 2) & 1, i = m & 3;
  return hi * 128 + mt * 16 + rq * 4 + i;
}

// ---------------- K1: rel-pos bias MLP -> permuted f16 table ----------------
__global__ void k_bias(const float* __restrict__ rel, const float* __restrict__ fc1w,
                       const float* __restrict__ fc1b, const float* __restrict__ fc2w,
                       const float* __restrict__ fc2b, f16* __restrict__ biasp) {
  int n = blockIdx.x, m = threadIdx.x;
  float r0 = rel[(n*256 + m)*2 + 0];
  float r1 = rel[(n*256 + m)*2 + 1];
  float a0 = fc2b[0], a1 = fc2b[1], a2 = fc2b[2], a3 = fc2b[3];
  for (int i = 0; i < 128; ++i) {
    float h = fmaf(r0, fc1w[i], fmaf(r1, fc1w[128 + i], fc1b[i]));
    float t = tanhf(0.7978845608028654f * (h + 0.044715f * h * h * h));
    float g = 0.5f * h * (1.0f + t);
    a0 = fmaf(g, fc2w[i*4 + 0], a0);
    a1 = fmaf(g, fc2w[i*4 + 1], a1);
    a2 = fmaf(g, fc2w[i*4 + 2], a2);
    a3 = fmaf(g, fc2w[i*4 + 3], a3);
  }
  int p = permidx(m);
  biasp[(0*256 + n)*256 + p] = (f16)a0;
  biasp[(1*256 + n)*256 + p] = (f16)a1;
  biasp[(2*256 + n)*256 + p] = (f16)a2;
  biasp[(3*256 + n)*256 + p] = (f16)a3;
}

// ---------------- K2: weight transposes (fp32 -> fp16) ----------------
__global__ void k_transpose(const float* __restrict__ qkvw, const float* __restrict__ projw,
                            f16* __restrict__ wt, f16* __restrict__ pwt) {
  int idx = blockIdx.x*256 + threadIdx.x;        // 0..65535
  if (idx < 49152) {                             // Wt[col][k] = qkv_w[k][col]
    int col = idx >> 7, k = idx & 127;
    wt[idx] = (f16)qkvw[k*384 + col];
  } else {
    int p = idx - 49152;                         // PWt[col][k] = proj_w[k][col]
    int col = p >> 7, k = p & 127;
    pwt[p] = (f16)projw[k*128 + col];
  }
}

// ---------------- K3: mask fp32 -> permuted f16 ----------------
// thread t handles one (w,n,hi,mt): 16 outputs (rq,i)
__global__ void k_perm(const float* __restrict__ mask, f16* __restrict__ maskp) {
  int t = blockIdx.x*256 + threadIdx.x;          // 0..262143
  int mt = t & 7, hi = (t >> 3) & 1, n = (t >> 4) & 255, w = t >> 12;
  const float* src = mask + (size_t)(w*256 + n)*256;
  f16* dst = maskp + ((size_t)(w*256 + n)*2 + hi)*128 + mt*16;
  #pragma unroll
  for (int rq = 0; rq < 4; ++rq) {
    f32x4 v = *(const f32x4*)(src + mt*32 + rq*8 + hi*4);
    #pragma unroll
    for (int i = 0; i < 4; ++i) dst[rq*4 + i] = (f16)v[i];
  }
}

// ---------------- K4: QKV GEMM (swapped operands) + global sumsq(q),sumsq(k) ----------------
// Wave computes 32 x-rows x 384 cols. A = Wt-frag (rows = out-cols), B = x-frag (cols = x-rows).
// C: col=lane&31 = x-row (m0+ln), reg r -> out-col ct*32 + (r&3)+8*(r>>2)+4*hi.
__global__ __launch_bounds__(512, 2)
void k_qkv(const float* __restrict__ x, const f16* __restrict__ wt,
           const float* __restrict__ qkvb, f16* __restrict__ qkv,
           float* __restrict__ norms) {
  int tid = threadIdx.x;
  int wv = tid >> 6, lane = tid & 63;
  int ln = lane & 31, hi = lane >> 5;
  int row = (blockIdx.x*8 + wv)*32 + ln;
  int b_ = row >> 8, n = row & 255;

  // load this lane's x-row halves (k = ks*16 + hi*8 + j), cvt to f16
  f16x8 xf[8];
  const float* xr = x + (size_t)row*128 + hi*8;
  #pragma unroll
  for (int ks = 0; ks < 8; ++ks) {
    f32x4 a = *(const f32x4*)(xr + ks*16);
    f32x4 b2 = *(const f32x4*)(xr + ks*16 + 4);
    f16x8 v;
    #pragma unroll
    for (int j = 0; j < 4; ++j) { v[j] = (f16)a[j]; v[j+4] = (f16)b2[j]; }
    xf[ks] = v;
  }

  float sq = 0.f, sk = 0.f;
  #pragma unroll 1
  for (int ct = 0; ct < 12; ++ct) {
    f32x16 acc;
    #pragma unroll
    for (int g = 0; g < 4; ++g) {
      f32x4 qb = *(const f32x4*)(qkvb + ct*32 + g*8 + hi*4);
      #pragma unroll
      for (int i = 0; i < 4; ++i) acc[g*4 + i] = qb[i];
    }
    const f16* wrow = wt + (size_t)(ct*32 + ln)*128 + hi*8;
    #pragma unroll
    for (int ks = 0; ks < 8; ++ks) {
      f16x8 wf = *(const f16x8*)(wrow + ks*16);
      acc = __builtin_amdgcn_mfma_f32_32x32x16_f16(wf, xf[ks], acc, 0, 0, 0);
    }
    int which = ct >> 2, hh = ct & 3;
    if (which == 0) {
      #pragma unroll
      for (int r = 0; r < 16; ++r) sq = fmaf(acc[r], acc[r], sq);
    } else if (which == 1) {
      #pragma unroll
      for (int r = 0; r < 16; ++r) sk = fmaf(acc[r], acc[r], sk);
    }
    if (which < 2) {   // q,k: [b][h][n][32], f16x4 vector stores
      f16* dst = qkv + (size_t)which*QSZ + ((size_t)(b_*4 + hh)*256 + n)*32 + hi*4;
      #pragma unroll
      for (int g = 0; g < 4; ++g) {
        f16x4 pk;
        #pragma unroll
        for (int i = 0; i < 4; ++i) pk[i] = (f16)acc[g*4 + i];
        *(f16x4*)(dst + g*8) = pk;
      }
    } else {           // v: transposed [b][h][32dd][256n]
      f16* dst = qkv + 2ull*QSZ + ((size_t)(b_*4 + hh)*32)*256 + n;
      #pragma unroll
      for (int g = 0; g < 4; ++g) {
        #pragma unroll
        for (int i = 0; i < 4; ++i) {
          int dd = g*8 + hi*4 + i;
          dst[(size_t)dd*256] = (f16)acc[g*4 + i];
        }
      }
    }
  }
  #pragma unroll
  for (int o = 32; o > 0; o >>= 1) { sq += __shfl_xor(sq, o); sk += __shfl_xor(sk, o); }
  if (lane == 0) { atomicAdd(norms + 0, sq); atomicAdd(norms + 1, sk); }
}

// ---------------- K5: fused window attention + proj (flash-chunked, barrier-free) ----------------
#define QKTILE(S, MT) { \
  f32x16 c; \
  _Pragma("unroll") for (int r_ = 0; r_ < 16; ++r_) c[r_] = 0.f; \
  const f16* krow = kbase + (size_t)((MT)*32 + ln)*32 + hi*8; \
  f16x8 ka0 = *(const f16x8*)(krow); \
  f16x8 ka1 = *(const f16x8*)(krow + 16); \
  c = __builtin_amdgcn_mfma_f32_32x32x16_f16(ka0, qf0, c, 0, 0, 0); \
  c = __builtin_amdgcn_mfma_f32_32x32x16_f16(ka1, qf1, c, 0, 0, 0); \
  f16x8 bp0 = *(const f16x8*)(bprow + (MT)*16); \
  f16x8 bp1 = *(const f16x8*)(bprow + (MT)*16 + 8); \
  f16x8 mp0 = *(const f16x8*)(mprow + (MT)*16); \
  f16x8 mp1 = *(const f16x8*)(mprow + (MT)*16 + 8); \
  _Pragma("unroll") for (int r_ = 0; r_ < 8; ++r_) { \
    float v_ = fmaf(c[r_], scale, (float)bp0[r_] + (float)mp0[r_]); \
    S[r_] = v_; mx = fmaxf(mx, v_); } \
  _Pragma("unroll") for (int r_ = 0; r_ < 8; ++r_) { \
    float v_ = fmaf(c[8 + r_], scale, (float)bp1[r_] + (float)mp1[r_]); \
    S[8 + r_] = v_; mx = fmaxf(mx, v_); } \
}

#define PVSTEP(S, BASE, KS) { \
  u32 w0 = pkh(S[(BASE)+0], S[(BASE)+1]); \
  u32 w1 = pkh(S[(BASE)+4], S[(BASE)+5]); \
  u32 w2 = pkh(S[(BASE)+2], S[(BASE)+3]); \
  u32 w3 = pkh(S[(BASE)+6], S[(BASE)+7]); \
  asm volatile("v_permlane32_swap_b32 %0, %1" : "+v"(w0), "+v"(w1)); \
  asm volatile("v_permlane32_swap_b32 %0, %1" : "+v"(w2), "+v"(w3)); \
  u32x4 av; av[0] = w0; av[1] = w2; av[2] = w1; av[3] = w3; \
  f16x8 afrag = __builtin_bit_cast(f16x8, av); \
  f16x8 vfrag = *(const f16x8*)(vbase + (KS)*16 + hi*8); \
  oacc = __builtin_amdgcn_mfma_f32_32x32x16_f16(afrag, vfrag, oacc, 0, 0, 0); \
}

__global__ __launch_bounds__(512, 2)
void k_attn(const f16* __restrict__ qkv, const f16* __restrict__ biasp,
            const f16* __restrict__ maskp, const f16* __restrict__ pwt,
            const float* __restrict__ projb, const float* __restrict__ norms,
            const float* __restrict__ taup, float* __restrict__ out) {
  __shared__ f16 outs[32768];  // swizzled attn-out: elem(n,c) at n*128 + ((c>>3)^(n&7))*8 + (c&7)

  int b = blockIdx.x, w = b & 63;
  int tid = threadIdx.x;
  int wv = tid >> 6, lane = tid & 63;
  int ln = lane & 31, hi = lane >> 5;
  int n0 = wv * 32;
  int nrow = n0 + ln;

  float tau = fmaxf(taup[0], 0.01f);
  float scale = 1.0f / (sqrtf(norms[0]) * sqrtf(norms[1]) * tau);

  #pragma unroll 1
  for (int h = 0; h < 4; ++h) {
    const f16* qrow = qkv + (size_t)(b*4 + h)*8192 + (size_t)nrow*32 + hi*8;
    f16x8 qf0 = *(const f16x8*)(qrow);
    f16x8 qf1 = *(const f16x8*)(qrow + 16);
    const f16* kbase = qkv + QSZ + (size_t)(b*4 + h)*8192;
    const f16* vbase = qkv + 2ull*QSZ + ((size_t)(b*4 + h)*32 + ln)*256;
    const f16* bprow = biasp + ((size_t)(h*256 + nrow)*2 + hi)*128;
    const f16* mprow = maskp + ((size_t)(w*256 + nrow)*2 + hi)*128;

    float m_run = -3e38f, sum = 0.f;
    f32x16 oacc;
    #pragma unroll
    for (int r = 0; r < 16; ++r) oacc[r] = 0.f;

    #pragma unroll 1
    for (int ch = 0; ch < 4; ++ch) {
      float mx = -3e38f;
      f32x16 s0, s1;
      QKTILE(s0, ch*2);
      QKTILE(s1, ch*2 + 1);
      mx = fmaxf(mx, __shfl_xor(mx, 32));
      float mnew = fmaxf(m_run, mx);
      float corr = __expf(m_run - mnew);
      m_run = mnew;
      sum *= corr;
      #pragma unroll
      for (int r = 0; r < 16; ++r) oacc[r] *= corr;
      #pragma unroll
      for (int r = 0; r < 16; ++r) { float p = __expf(s0[r] - mnew); s0[r] = p; sum += p; }
      #pragma unroll
      for (int r = 0; r < 16; ++r) { float p = __expf(s1[r] - mnew); s1[r] = p; sum += p; }
      PVSTEP(s0, 0, ch*4 + 0);
      PVSTEP(s0, 8, ch*4 + 1);
      PVSTEP(s1, 0, ch*4 + 2);
      PVSTEP(s1, 8, ch*4 + 3);
    }

    sum += __shfl_xor(sum, 32);
    float rs = 1.0f / sum;
    #pragma unroll
    for (int r = 0; r < 16; ++r) {
      int nn = n0 + (r & 3) + 8*(r >> 2) + 4*hi;
      int c = h*32 + ln;
      outs[nn*128 + ((((c >> 3) ^ (nn & 7))) << 3) + (c & 7)] = (f16)(oacc[r] * rs);
    }
  }

  // fused proj: rows are wave-private (no barrier needed)
  {
    f16x8 afr[8];
    #pragma unroll
    for (int ks = 0; ks < 8; ++ks)
      afr[ks] = *(const f16x8*)&outs[nrow*128 + (((2*ks + hi) ^ (nrow & 7)) << 3)];
    #pragma unroll 1
    for (int ct = 0; ct < 4; ++ct) {
      int cout = ct*32 + ln;
      float pb = projb[cout];
      f32x16 pacc;
      #pragma unroll
      for (int r = 0; r < 16; ++r) pacc[r] = pb;
      const f16* prow = pwt + (size_t)cout*128 + hi*8;
      #pragma unroll
      for (int ks = 0; ks < 8; ++ks) {
        f16x8 bfr = *(const f16x8*)(prow + ks*16);
        pacc = __builtin_amdgcn_mfma_f32_32x32x16_f16(afr[ks], bfr, pacc, 0, 0, 0);
      }
      #pragma unroll
      for (int r = 0; r < 16; ++r) {
        int nn = n0 + (r & 3) + 8*(r >> 2) + 4*hi;
        out[((size_t)b*256 + nn)*128 + cout] = pacc[r];
      }
    }
  }
}

// ---------------- launch ----------------
extern "C" void kernel_launch(void* const* d_in, const int* in_sizes, int n_in,
                              void* d_out, int out_size, void* d_ws, size_t ws_size,
                              hipStream_t stream) {
  const float* x     = (const float*)d_in[0];
  const float* mask  = (const float*)d_in[1];
  const float* rel   = (const float*)d_in[2];
  const float* qkvw  = (const float*)d_in[3];
  const float* qkvb  = (const float*)d_in[4];
  const float* projw = (const float*)d_in[5];
  const float* projb = (const float*)d_in[6];
  const float* fc1w  = (const float*)d_in[7];
  const float* fc1b  = (const float*)d_in[8];
  const float* fc2w  = (const float*)d_in[9];
  const float* fc2b  = (const float*)d_in[10];
  const float* tau   = (const float*)d_in[11];
  float* outp = (float*)d_out;
  char* ws = (char*)d_ws;

  float* norms  = (float*)(ws + OFF_NORM);
  f16*   wt     = (f16*)(ws + OFF_WT);
  f16*   pwt    = (f16*)(ws + OFF_PWT);
  f16*   biasp  = (f16*)(ws + OFF_BIASP);
  f16*   maskp  = (f16*)(ws + OFF_MASKP);
  f16*   qkv    = (f16*)(ws + OFF_QKV);

  hipMemsetAsync(norms, 0, 8, stream);
  k_bias<<<256, 256, 0, stream>>>(rel, fc1w, fc1b, fc2w, fc2b, biasp);
  k_transpose<<<256, 256, 0, stream>>>(qkvw, projw, wt, pwt);
  k_perm<<<1024, 256, 0, stream>>>(mask, maskp);
  k_qkv<<<1024, 512, 0, stream>>>(x, wt, qkvb, qkv, norms);
  k_attn<<<1024, 512, 0, stream>>>(qkv, biasp, maskp, pwt, projb, norms, tau, outp);
}